// Round 16
// baseline (359.377 us; speedup 1.0000x reference)
//
#include <hip/hip_runtime.h>

typedef __attribute__((ext_vector_type(8))) short bf16x8;
typedef __attribute__((ext_vector_type(4))) float f32x4;

#if defined(__has_builtin)
#if __has_builtin(__builtin_amdgcn_global_load_lds)
#define HAVE_GLL 1
#endif
#endif

__device__ __forceinline__ ushort f2bf(float f) {
    unsigned u = __float_as_uint(f);
    u += 0x7fffu + ((u >> 16) & 1u);   // round-to-nearest-even
    return (ushort)(u >> 16);
}

// global->LDS 16B stage. GLL path: lbase is wave-uniform, HW adds lane*16.
__device__ __forceinline__ void stage16(const ushort* __restrict__ g, ushort* lbase, int lane) {
#ifdef HAVE_GLL
    __builtin_amdgcn_global_load_lds((const __attribute__((address_space(1))) void*)g,
                                     (__attribute__((address_space(3))) void*)lbase,
                                     16, 0, 0);
#else
    *(float4*)(lbase + lane * 8) = *(const float4*)g;
#endif
}

// ---------------- K0: f32 -> bf16 weight conversion ----------------
__global__ void k_cvt(const float* __restrict__ src, ushort* __restrict__ dst, int n4) {
    int i = blockIdx.x * blockDim.x + threadIdx.x;
    if (i >= n4) return;
    float4 v = ((const float4*)src)[i];
    ushort4 o;
    o.x = f2bf(v.x); o.y = f2bf(v.y); o.z = f2bf(v.z); o.w = f2bf(v.w);
    ((ushort4*)dst)[i] = o;
}

// ---------------- K1: per-row stats + params + layer_input ----------------
// (r12 proven, byte-identical) 512 blocks x 512 threads. 16 rows/block; wave
// wq owns a k-eighth; fragments built directly in registers; no k-loop
// barriers.
__global__ __launch_bounds__(512) void k_stats(
    const float* __restrict__ x,        // [8192][8192]
    const ushort* __restrict__ wallb,   // [32][8192] bf16
    const float* __restrict__ b_all,    // [32]
    const float* __restrict__ a_pre, const float* __restrict__ a_post,
    const float* __restrict__ a_res,
    const float* __restrict__ perm,     // [24][16]
    float* __restrict__ params,         // [8192][24]: h_pre[4] h_post[4] Hm[16]
    ushort* __restrict__ li)            // [8192][2048] bf16
{
    __shared__ float dots[8][16][33];
    __shared__ float ssq_s[8][16];
    __shared__ float hpre_l[16][4];

    const int tid = threadIdx.x;
    const int lane = tid & 63;
    const int wq = tid >> 6;            // k-eighth 0..7
    const int r = lane & 15;            // x-row / W-row within group
    const int kg = lane >> 4;           // k-subgroup 0..3
    const int brow = blockIdx.x * 16;

    const float* xp = x + (size_t)(brow + r) * 8192 + wq * 1024 + kg * 8;
    const ushort* wp0 = wallb + (size_t)r * 8192 + wq * 1024 + kg * 8;
    const ushort* wp1 = wp0 + 16 * 8192;

    f32x4 acc0 = {}, acc1 = {};
    float ssq = 0.f;

#pragma unroll 4
    for (int s = 0; s < 32; ++s) {
        const int off = s * 32;
        float4 a0 = *(const float4*)(xp + off);
        float4 a1 = *(const float4*)(xp + off + 4);
        float va[8] = {a0.x, a0.y, a0.z, a0.w, a1.x, a1.y, a1.z, a1.w};
        union { ushort u[8]; bf16x8 v; } av;
#pragma unroll
        for (int j = 0; j < 8; ++j) { ssq += va[j] * va[j]; av.u[j] = f2bf(va[j]); }
        bf16x8 b0 = *(const bf16x8*)(wp0 + off);
        bf16x8 b1 = *(const bf16x8*)(wp1 + off);
        acc0 = __builtin_amdgcn_mfma_f32_16x16x32_bf16(av.v, b0, acc0, 0, 0, 0);
        acc1 = __builtin_amdgcn_mfma_f32_16x16x32_bf16(av.v, b1, acc1, 0, 0, 0);
    }

    ssq += __shfl_xor(ssq, 16);
    ssq += __shfl_xor(ssq, 32);
    if (lane < 16) ssq_s[wq][r] = ssq;
#pragma unroll
    for (int i = 0; i < 4; ++i) {
        dots[wq][kg * 4 + i][r] = acc0[i];
        dots[wq][kg * 4 + i][16 + r] = acc1[i];
    }
    __syncthreads();

    if (tid < 16) {
        float s = 0.f;
#pragma unroll
        for (int q = 0; q < 8; ++q) s += ssq_s[q][tid];
        float inv_rms = rsqrtf(s * (1.0f / 8192.0f) + 1.1920929e-7f);
        float pj[32];
#pragma unroll
        for (int j = 0; j < 32; ++j) {
            float d = 0.f;
#pragma unroll
            for (int q = 0; q < 8; ++q) d += dots[q][tid][j];
            pj[j] = d * inv_rms;
        }
        float ap = a_pre[0], apo = a_post[0], ar = a_res[0];
        float hpre[4], hpost[4];
#pragma unroll
        for (int n = 0; n < 4; ++n) {
            hpre[n] = 1.0f / (1.0f + expf(-(ap * pj[n] + b_all[n])));
            hpost[n] = 2.0f / (1.0f + expf(-(apo * pj[4 + n] + b_all[4 + n])));
        }
        float z[24]; float mx = -1e30f;
#pragma unroll
        for (int p = 0; p < 24; ++p) { z[p] = ar * pj[8 + p] + b_all[8 + p]; mx = fmaxf(mx, z[p]); }
        float se = 0.f;
#pragma unroll
        for (int p = 0; p < 24; ++p) { z[p] = expf(z[p] - mx); se += z[p]; }
        float isum = 1.0f / se;
        float Hr[16];
#pragma unroll
        for (int e = 0; e < 16; ++e) Hr[e] = 0.f;
#pragma unroll
        for (int p = 0; p < 24; ++p) {
            float a = z[p] * isum;
#pragma unroll
            for (int e = 0; e < 16; ++e) Hr[e] += a * perm[p * 16 + e];
        }
        float* P = params + (size_t)(brow + tid) * 24;
#pragma unroll
        for (int n = 0; n < 4; ++n) { P[n] = hpre[n]; P[4 + n] = hpost[n]; hpre_l[tid][n] = hpre[n]; }
#pragma unroll
        for (int n = 0; n < 4; ++n)
#pragma unroll
            for (int m = 0; m < 4; ++m)
                P[8 + n * 4 + m] = Hr[n * 4 + m] - hpost[n] * hpre[m];
    }
    __syncthreads();

    // layer_input phase: block's x rows just streamed -> L2/L3-warm.
    const int c = tid * 4;
#pragma unroll 4
    for (int rr = 0; rr < 16; ++rr) {
        float h0 = hpre_l[rr][0], h1 = hpre_l[rr][1], h2 = hpre_l[rr][2], h3 = hpre_l[rr][3];
        const float* xr = x + (size_t)(brow + rr) * 8192 + c;
        float4 a0 = *(const float4*)(xr);
        float4 a1 = *(const float4*)(xr + 2048);
        float4 a2 = *(const float4*)(xr + 4096);
        float4 a3 = *(const float4*)(xr + 6144);
        ushort4 ob;
        ob.x = f2bf(h0 * a0.x + h1 * a1.x + h2 * a2.x + h3 * a3.x);
        ob.y = f2bf(h0 * a0.y + h1 * a1.y + h2 * a2.y + h3 * a3.y);
        ob.z = f2bf(h0 * a0.z + h1 * a1.z + h2 * a2.z + h3 * a3.z);
        ob.w = f2bf(h0 * a0.w + h1 * a1.w + h2 * a2.w + h3 * a3.w);
        *(ushort4*)(li + (size_t)(brow + rr) * 2048 + c) = ob;
    }
}

// ---------------- K3: GEMM (li @ W_layer^T) + fused final combine ----------------
// Mainloop: EXACT round-7 configuration (128x128, BK=64, 4 waves, q=4 dbuf,
// one barrier per K-tile). Epilogue: round-12 proven full-tile one-shot
// swizzled lo round-trip + r15 nontemporal out stores (keeps x L3-resident
// across replays; k_stats -17us). NEW (r16): phase-2 unroll 2->4 — more
// independent x loads in flight (epilogue latency residual); VGPR headroom
// free since LDS (77KB -> 2 blocks/CU) binds occupancy, not VGPR.
__global__ __launch_bounds__(256) void k_gemm_out(
    const ushort* __restrict__ liA,    // [8192][2048] bf16
    const ushort* __restrict__ WB,     // [2048][2048] bf16 (c,k) = B^T layout
    const float* __restrict__ b_layer, // [2048]
    const float* __restrict__ params,  // [8192][24]
    const float* __restrict__ x,       // [8192][8192]
    float* __restrict__ out)           // [8192][4][2048]
{
    __shared__ __align__(16) ushort ABlds[4][128 * 64];  // A=buf 0/1, B=buf 2/3; 64KB
    __shared__ float Plds[128 * 25];
    __shared__ float bl_s[128];

    const int tid = threadIdx.x;
    const int ln = tid & 63;
    const int wv = tid >> 6;
    const int brow = blockIdx.x * 128;
    const int bcol = blockIdx.y * 128;

    for (int i = tid; i < 128 * 24; i += 256) {
        int r = i / 24, j = i - r * 24;
        Plds[r * 25 + j] = params[(size_t)(brow + r) * 24 + j];
    }
    if (tid < 128) bl_s[tid] = b_layer[bcol + tid];

    f32x4 acc[4][4] = {};

    const int srow = ln >> 3;                       // staging row within 8-row group
    const int scol = ((ln & 7) ^ srow) * 8;         // pre-swizzled source col
    const int wm = wv >> 1, wn = wv & 1;
    const int fr = ln & 15, fq = ln >> 4;
    const int swz = (fr & 7) << 3;                  // read-side XOR (ushort units)

    auto do_stage = [&](int buf, int k0) {
#pragma unroll
        for (int q = 0; q < 4; ++q) {
            int row = wv * 32 + q * 8 + srow;
            stage16(liA + (size_t)(brow + row) * 2048 + k0 + scol, &ABlds[buf][wv * 2048 + q * 512], ln);
            stage16(WB + (size_t)(bcol + row) * 2048 + k0 + scol, &ABlds[2 + buf][wv * 2048 + q * 512], ln);
        }
    };

    do_stage(0, 0);
    __syncthreads();

    int cur = 0;
    for (int k0 = 0; k0 < 2048; k0 += 64) {
        if (k0 + 64 < 2048) do_stage(cur ^ 1, k0 + 64);   // prefetch flies under MFMA
#pragma unroll
        for (int kk = 0; kk < 64; kk += 32) {
            bf16x8 af[4], bg[4];
#pragma unroll
            for (int mi = 0; mi < 4; ++mi)
                af[mi] = *(const bf16x8*)&ABlds[cur][(wm * 64 + mi * 16 + fr) * 64 + ((kk + fq * 8) ^ swz)];
#pragma unroll
            for (int ni = 0; ni < 4; ++ni)
                bg[ni] = *(const bf16x8*)&ABlds[2 + cur][(wn * 64 + ni * 16 + fr) * 64 + ((kk + fq * 8) ^ swz)];
#pragma unroll
            for (int mi = 0; mi < 4; ++mi)
#pragma unroll
                for (int ni = 0; ni < 4; ++ni)
                    acc[mi][ni] = __builtin_amdgcn_mfma_f32_16x16x32_bf16(bg[ni], af[mi], acc[mi][ni], 0, 0, 0);
        }
        __syncthreads();         // one barrier per K-tile: drains prefetch + guards reuse
        cur ^= 1;
    }
    __syncthreads();   // all waves done with AB before lo reuse

    // ---- Epilogue phase 1: acc+bias -> lo_lds[128][128] f32 (64KB, one shot) ----
    // Swizzle: logical chunk c (16B) of row rl stored at PHYSICAL chunk c^(rl&7).
    float* lo_lds = (float*)&ABlds[0][0];
#pragma unroll
    for (int mi = 0; mi < 4; ++mi) {
#pragma unroll
        for (int ni = 0; ni < 4; ++ni) {
            const int rl = wm * 64 + mi * 16 + fr;            // 0..127
            const int c_loc = wn * 64 + ni * 16 + fq * 4;     // 0..127
            const int slot = (((c_loc >> 2) ^ (rl & 7)) << 2);
            float4 bl = *(const float4*)&bl_s[c_loc];
            float4 v;
            v.x = acc[mi][ni][0] + bl.x;
            v.y = acc[mi][ni][1] + bl.y;
            v.z = acc[mi][ni][2] + bl.z;
            v.w = acc[mi][ni][3] + bl.w;
            *(float4*)&lo_lds[rl * 128 + slot] = v;
        }
    }
    __syncthreads();

    // ---- Epilogue phase 2: coalesced streaming combine (wave owns 32 rows) ----
    // lo read at PHYSICAL chunk lc32 -> logical chunk lc32^(rl2&7) = c_act.
    const int half = ln >> 5;
    const int lc32 = ln & 31;
#pragma unroll 4
    for (int rr = 0; rr < 32; rr += 2) {
        const int rl2 = wv * 32 + rr + half;                    // 0..127
        const size_t t = (size_t)(brow + rl2);
        const int c_act = ((lc32 ^ (rl2 & 7)) << 2);            // logical column
        float4 lo4 = *(const float4*)&lo_lds[rl2 * 128 + (lc32 << 2)];
        const float* P = &Plds[rl2 * 25];
        const float* xt = x + t * 8192 + bcol + c_act;
        float* ot = out + t * 8192 + bcol + c_act;
        float4 x0 = *(const float4*)(xt);
        float4 x1 = *(const float4*)(xt + 2048);
        float4 x2 = *(const float4*)(xt + 4096);
        float4 x3 = *(const float4*)(xt + 6144);
#pragma unroll
        for (int n = 0; n < 4; ++n) {
            float hp = P[4 + n];
            float h0 = P[8 + n * 4 + 0], h1 = P[8 + n * 4 + 1];
            float h2 = P[8 + n * 4 + 2], h3 = P[8 + n * 4 + 3];
            f32x4 v;
            v[0] = hp * lo4.x + h0 * x0.x + h1 * x1.x + h2 * x2.x + h3 * x3.x;
            v[1] = hp * lo4.y + h0 * x0.y + h1 * x1.y + h2 * x2.y + h3 * x3.y;
            v[2] = hp * lo4.z + h0 * x0.z + h1 * x1.z + h2 * x2.z + h3 * x3.z;
            v[3] = hp * lo4.w + h0 * x0.w + h1 * x1.w + h2 * x2.w + h3 * x3.w;
            __builtin_nontemporal_store(v, (f32x4*)(ot + (size_t)n * 2048));
        }
    }
}

extern "C" void kernel_launch(void* const* d_in, const int* in_sizes, int n_in,
                              void* d_out, int out_size, void* d_ws, size_t ws_size,
                              hipStream_t stream) {
    const float* x       = (const float*)d_in[0];
    const float* W_all   = (const float*)d_in[1];
    const float* b_all   = (const float*)d_in[2];
    const float* a_pre   = (const float*)d_in[3];
    const float* a_post  = (const float*)d_in[4];
    const float* a_res   = (const float*)d_in[5];
    const float* perm    = (const float*)d_in[6];
    const float* W_layer = (const float*)d_in[7];
    const float* b_layer = (const float*)d_in[8];
    float* out = (float*)d_out;

    char* ws = (char*)d_ws;
    ushort* wall_b   = (ushort*)(ws);                                        // 512 KB
    ushort* wlayer_b = (ushort*)(ws + (512u << 10));                         // 8 MB
    float*  params   = (float*)(ws + (512u << 10) + (8u << 20));             // 768 KB
    ushort* li       = (ushort*)(ws + (512u << 10) + (8u << 20) + (768u << 10)); // 32 MB

    k_cvt<<<dim3(256), dim3(256), 0, stream>>>(W_all, wall_b, 65536);
    k_cvt<<<dim3(4096), dim3(256), 0, stream>>>(W_layer, wlayer_b, 1048576);
    k_stats<<<dim3(512), dim3(512), 0, stream>>>(x, wall_b, b_all, a_pre, a_post, a_res,
                                                 perm, params, li);
    k_gemm_out<<<dim3(64, 16), dim3(256), 0, stream>>>(li, wlayer_b, b_layer, params, x, out);
}

// Round 17
// 277.496 us; speedup vs baseline: 1.2951x; 1.2951x over previous
//
#include <hip/hip_runtime.h>

typedef __attribute__((ext_vector_type(8))) short bf16x8;
typedef __attribute__((ext_vector_type(4))) float f32x4;

#if defined(__has_builtin)
#if __has_builtin(__builtin_amdgcn_global_load_lds)
#define HAVE_GLL 1
#endif
#endif

__device__ __forceinline__ ushort f2bf(float f) {
    unsigned u = __float_as_uint(f);
    u += 0x7fffu + ((u >> 16) & 1u);   // round-to-nearest-even
    return (ushort)(u >> 16);
}

// global->LDS 16B stage. GLL path: lbase is wave-uniform, HW adds lane*16.
__device__ __forceinline__ void stage16(const ushort* __restrict__ g, ushort* lbase, int lane) {
#ifdef HAVE_GLL
    __builtin_amdgcn_global_load_lds((const __attribute__((address_space(1))) void*)g,
                                     (__attribute__((address_space(3))) void*)lbase,
                                     16, 0, 0);
#else
    *(float4*)(lbase + lane * 8) = *(const float4*)g;
#endif
}

// ---------------- K0: f32 -> bf16 weight conversion ----------------
__global__ void k_cvt(const float* __restrict__ src, ushort* __restrict__ dst, int n4) {
    int i = blockIdx.x * blockDim.x + threadIdx.x;
    if (i >= n4) return;
    float4 v = ((const float4*)src)[i];
    ushort4 o;
    o.x = f2bf(v.x); o.y = f2bf(v.y); o.z = f2bf(v.z); o.w = f2bf(v.w);
    ((ushort4*)dst)[i] = o;
}

// ---------------- K1: per-row stats + params + layer_input ----------------
// (r12 proven, byte-identical) 512 blocks x 512 threads. 16 rows/block; wave
// wq owns a k-eighth; fragments built directly in registers; no k-loop
// barriers.
__global__ __launch_bounds__(512) void k_stats(
    const float* __restrict__ x,        // [8192][8192]
    const ushort* __restrict__ wallb,   // [32][8192] bf16
    const float* __restrict__ b_all,    // [32]
    const float* __restrict__ a_pre, const float* __restrict__ a_post,
    const float* __restrict__ a_res,
    const float* __restrict__ perm,     // [24][16]
    float* __restrict__ params,         // [8192][24]: h_pre[4] h_post[4] Hm[16]
    ushort* __restrict__ li)            // [8192][2048] bf16
{
    __shared__ float dots[8][16][33];
    __shared__ float ssq_s[8][16];
    __shared__ float hpre_l[16][4];

    const int tid = threadIdx.x;
    const int lane = tid & 63;
    const int wq = tid >> 6;            // k-eighth 0..7
    const int r = lane & 15;            // x-row / W-row within group
    const int kg = lane >> 4;           // k-subgroup 0..3
    const int brow = blockIdx.x * 16;

    const float* xp = x + (size_t)(brow + r) * 8192 + wq * 1024 + kg * 8;
    const ushort* wp0 = wallb + (size_t)r * 8192 + wq * 1024 + kg * 8;
    const ushort* wp1 = wp0 + 16 * 8192;

    f32x4 acc0 = {}, acc1 = {};
    float ssq = 0.f;

#pragma unroll 4
    for (int s = 0; s < 32; ++s) {
        const int off = s * 32;
        float4 a0 = *(const float4*)(xp + off);
        float4 a1 = *(const float4*)(xp + off + 4);
        float va[8] = {a0.x, a0.y, a0.z, a0.w, a1.x, a1.y, a1.z, a1.w};
        union { ushort u[8]; bf16x8 v; } av;
#pragma unroll
        for (int j = 0; j < 8; ++j) { ssq += va[j] * va[j]; av.u[j] = f2bf(va[j]); }
        bf16x8 b0 = *(const bf16x8*)(wp0 + off);
        bf16x8 b1 = *(const bf16x8*)(wp1 + off);
        acc0 = __builtin_amdgcn_mfma_f32_16x16x32_bf16(av.v, b0, acc0, 0, 0, 0);
        acc1 = __builtin_amdgcn_mfma_f32_16x16x32_bf16(av.v, b1, acc1, 0, 0, 0);
    }

    ssq += __shfl_xor(ssq, 16);
    ssq += __shfl_xor(ssq, 32);
    if (lane < 16) ssq_s[wq][r] = ssq;
#pragma unroll
    for (int i = 0; i < 4; ++i) {
        dots[wq][kg * 4 + i][r] = acc0[i];
        dots[wq][kg * 4 + i][16 + r] = acc1[i];
    }
    __syncthreads();

    if (tid < 16) {
        float s = 0.f;
#pragma unroll
        for (int q = 0; q < 8; ++q) s += ssq_s[q][tid];
        float inv_rms = rsqrtf(s * (1.0f / 8192.0f) + 1.1920929e-7f);
        float pj[32];
#pragma unroll
        for (int j = 0; j < 32; ++j) {
            float d = 0.f;
#pragma unroll
            for (int q = 0; q < 8; ++q) d += dots[q][tid][j];
            pj[j] = d * inv_rms;
        }
        float ap = a_pre[0], apo = a_post[0], ar = a_res[0];
        float hpre[4], hpost[4];
#pragma unroll
        for (int n = 0; n < 4; ++n) {
            hpre[n] = 1.0f / (1.0f + expf(-(ap * pj[n] + b_all[n])));
            hpost[n] = 2.0f / (1.0f + expf(-(apo * pj[4 + n] + b_all[4 + n])));
        }
        float z[24]; float mx = -1e30f;
#pragma unroll
        for (int p = 0; p < 24; ++p) { z[p] = ar * pj[8 + p] + b_all[8 + p]; mx = fmaxf(mx, z[p]); }
        float se = 0.f;
#pragma unroll
        for (int p = 0; p < 24; ++p) { z[p] = expf(z[p] - mx); se += z[p]; }
        float isum = 1.0f / se;
        float Hr[16];
#pragma unroll
        for (int e = 0; e < 16; ++e) Hr[e] = 0.f;
#pragma unroll
        for (int p = 0; p < 24; ++p) {
            float a = z[p] * isum;
#pragma unroll
            for (int e = 0; e < 16; ++e) Hr[e] += a * perm[p * 16 + e];
        }
        float* P = params + (size_t)(brow + tid) * 24;
#pragma unroll
        for (int n = 0; n < 4; ++n) { P[n] = hpre[n]; P[4 + n] = hpost[n]; hpre_l[tid][n] = hpre[n]; }
#pragma unroll
        for (int n = 0; n < 4; ++n)
#pragma unroll
            for (int m = 0; m < 4; ++m)
                P[8 + n * 4 + m] = Hr[n * 4 + m] - hpost[n] * hpre[m];
    }
    __syncthreads();

    // layer_input phase: block's x rows just streamed -> L2/L3-warm.
    const int c = tid * 4;
#pragma unroll 4
    for (int rr = 0; rr < 16; ++rr) {
        float h0 = hpre_l[rr][0], h1 = hpre_l[rr][1], h2 = hpre_l[rr][2], h3 = hpre_l[rr][3];
        const float* xr = x + (size_t)(brow + rr) * 8192 + c;
        float4 a0 = *(const float4*)(xr);
        float4 a1 = *(const float4*)(xr + 2048);
        float4 a2 = *(const float4*)(xr + 4096);
        float4 a3 = *(const float4*)(xr + 6144);
        ushort4 ob;
        ob.x = f2bf(h0 * a0.x + h1 * a1.x + h2 * a2.x + h3 * a3.x);
        ob.y = f2bf(h0 * a0.y + h1 * a1.y + h2 * a2.y + h3 * a3.y);
        ob.z = f2bf(h0 * a0.z + h1 * a1.z + h2 * a2.z + h3 * a3.z);
        ob.w = f2bf(h0 * a0.w + h1 * a1.w + h2 * a2.w + h3 * a3.w);
        *(ushort4*)(li + (size_t)(brow + rr) * 2048 + c) = ob;
    }
}

// ---------------- K3: GEMM (li @ W_layer^T) + fused final combine ----------------
// Mainloop: EXACT round-7 configuration (128x128, BK=64, 4 waves, q=4 dbuf,
// one barrier per K-tile). Epilogue: round-12 proven full-tile one-shot
// swizzled lo round-trip + r15 nontemporal out stores (keeps x L3-resident
// across replays). Phase-2 unroll stays at 2: r16's unroll-4 blew VGPR
// 92->160 -> occupancy 20->11% -> +85us. This is the proven best config.
__global__ __launch_bounds__(256) void k_gemm_out(
    const ushort* __restrict__ liA,    // [8192][2048] bf16
    const ushort* __restrict__ WB,     // [2048][2048] bf16 (c,k) = B^T layout
    const float* __restrict__ b_layer, // [2048]
    const float* __restrict__ params,  // [8192][24]
    const float* __restrict__ x,       // [8192][8192]
    float* __restrict__ out)           // [8192][4][2048]
{
    __shared__ __align__(16) ushort ABlds[4][128 * 64];  // A=buf 0/1, B=buf 2/3; 64KB
    __shared__ float Plds[128 * 25];
    __shared__ float bl_s[128];

    const int tid = threadIdx.x;
    const int ln = tid & 63;
    const int wv = tid >> 6;
    const int brow = blockIdx.x * 128;
    const int bcol = blockIdx.y * 128;

    for (int i = tid; i < 128 * 24; i += 256) {
        int r = i / 24, j = i - r * 24;
        Plds[r * 25 + j] = params[(size_t)(brow + r) * 24 + j];
    }
    if (tid < 128) bl_s[tid] = b_layer[bcol + tid];

    f32x4 acc[4][4] = {};

    const int srow = ln >> 3;                       // staging row within 8-row group
    const int scol = ((ln & 7) ^ srow) * 8;         // pre-swizzled source col
    const int wm = wv >> 1, wn = wv & 1;
    const int fr = ln & 15, fq = ln >> 4;
    const int swz = (fr & 7) << 3;                  // read-side XOR (ushort units)

    auto do_stage = [&](int buf, int k0) {
#pragma unroll
        for (int q = 0; q < 4; ++q) {
            int row = wv * 32 + q * 8 + srow;
            stage16(liA + (size_t)(brow + row) * 2048 + k0 + scol, &ABlds[buf][wv * 2048 + q * 512], ln);
            stage16(WB + (size_t)(bcol + row) * 2048 + k0 + scol, &ABlds[2 + buf][wv * 2048 + q * 512], ln);
        }
    };

    do_stage(0, 0);
    __syncthreads();

    int cur = 0;
    for (int k0 = 0; k0 < 2048; k0 += 64) {
        if (k0 + 64 < 2048) do_stage(cur ^ 1, k0 + 64);   // prefetch flies under MFMA
#pragma unroll
        for (int kk = 0; kk < 64; kk += 32) {
            bf16x8 af[4], bg[4];
#pragma unroll
            for (int mi = 0; mi < 4; ++mi)
                af[mi] = *(const bf16x8*)&ABlds[cur][(wm * 64 + mi * 16 + fr) * 64 + ((kk + fq * 8) ^ swz)];
#pragma unroll
            for (int ni = 0; ni < 4; ++ni)
                bg[ni] = *(const bf16x8*)&ABlds[2 + cur][(wn * 64 + ni * 16 + fr) * 64 + ((kk + fq * 8) ^ swz)];
#pragma unroll
            for (int mi = 0; mi < 4; ++mi)
#pragma unroll
                for (int ni = 0; ni < 4; ++ni)
                    acc[mi][ni] = __builtin_amdgcn_mfma_f32_16x16x32_bf16(bg[ni], af[mi], acc[mi][ni], 0, 0, 0);
        }
        __syncthreads();         // one barrier per K-tile: drains prefetch + guards reuse
        cur ^= 1;
    }
    __syncthreads();   // all waves done with AB before lo reuse

    // ---- Epilogue phase 1: acc+bias -> lo_lds[128][128] f32 (64KB, one shot) ----
    // Swizzle: logical chunk c (16B) of row rl stored at PHYSICAL chunk c^(rl&7).
    float* lo_lds = (float*)&ABlds[0][0];
#pragma unroll
    for (int mi = 0; mi < 4; ++mi) {
#pragma unroll
        for (int ni = 0; ni < 4; ++ni) {
            const int rl = wm * 64 + mi * 16 + fr;            // 0..127
            const int c_loc = wn * 64 + ni * 16 + fq * 4;     // 0..127
            const int slot = (((c_loc >> 2) ^ (rl & 7)) << 2);
            float4 bl = *(const float4*)&bl_s[c_loc];
            float4 v;
            v.x = acc[mi][ni][0] + bl.x;
            v.y = acc[mi][ni][1] + bl.y;
            v.z = acc[mi][ni][2] + bl.z;
            v.w = acc[mi][ni][3] + bl.w;
            *(float4*)&lo_lds[rl * 128 + slot] = v;
        }
    }
    __syncthreads();

    // ---- Epilogue phase 2: coalesced streaming combine (wave owns 32 rows) ----
    // lo read at PHYSICAL chunk lc32 -> logical chunk lc32^(rl2&7) = c_act.
    const int half = ln >> 5;
    const int lc32 = ln & 31;
#pragma unroll 2
    for (int rr = 0; rr < 32; rr += 2) {
        const int rl2 = wv * 32 + rr + half;                    // 0..127
        const size_t t = (size_t)(brow + rl2);
        const int c_act = ((lc32 ^ (rl2 & 7)) << 2);            // logical column
        float4 lo4 = *(const float4*)&lo_lds[rl2 * 128 + (lc32 << 2)];
        const float* P = &Plds[rl2 * 25];
        const float* xt = x + t * 8192 + bcol + c_act;
        float* ot = out + t * 8192 + bcol + c_act;
        float4 x0 = *(const float4*)(xt);
        float4 x1 = *(const float4*)(xt + 2048);
        float4 x2 = *(const float4*)(xt + 4096);
        float4 x3 = *(const float4*)(xt + 6144);
#pragma unroll
        for (int n = 0; n < 4; ++n) {
            float hp = P[4 + n];
            float h0 = P[8 + n * 4 + 0], h1 = P[8 + n * 4 + 1];
            float h2 = P[8 + n * 4 + 2], h3 = P[8 + n * 4 + 3];
            f32x4 v;
            v[0] = hp * lo4.x + h0 * x0.x + h1 * x1.x + h2 * x2.x + h3 * x3.x;
            v[1] = hp * lo4.y + h0 * x0.y + h1 * x1.y + h2 * x2.y + h3 * x3.y;
            v[2] = hp * lo4.z + h0 * x0.z + h1 * x1.z + h2 * x2.z + h3 * x3.z;
            v[3] = hp * lo4.w + h0 * x0.w + h1 * x1.w + h2 * x2.w + h3 * x3.w;
            __builtin_nontemporal_store(v, (f32x4*)(ot + (size_t)n * 2048));
        }
    }
}

extern "C" void kernel_launch(void* const* d_in, const int* in_sizes, int n_in,
                              void* d_out, int out_size, void* d_ws, size_t ws_size,
                              hipStream_t stream) {
    const float* x       = (const float*)d_in[0];
    const float* W_all   = (const float*)d_in[1];
    const float* b_all   = (const float*)d_in[2];
    const float* a_pre   = (const float*)d_in[3];
    const float* a_post  = (const float*)d_in[4];
    const float* a_res   = (const float*)d_in[5];
    const float* perm    = (const float*)d_in[6];
    const float* W_layer = (const float*)d_in[7];
    const float* b_layer = (const float*)d_in[8];
    float* out = (float*)d_out;

    char* ws = (char*)d_ws;
    ushort* wall_b   = (ushort*)(ws);                                        // 512 KB
    ushort* wlayer_b = (ushort*)(ws + (512u << 10));                         // 8 MB
    float*  params   = (float*)(ws + (512u << 10) + (8u << 20));             // 768 KB
    ushort* li       = (ushort*)(ws + (512u << 10) + (8u << 20) + (768u << 10)); // 32 MB

    k_cvt<<<dim3(256), dim3(256), 0, stream>>>(W_all, wall_b, 65536);
    k_cvt<<<dim3(4096), dim3(256), 0, stream>>>(W_layer, wlayer_b, 1048576);
    k_stats<<<dim3(512), dim3(512), 0, stream>>>(x, wall_b, b_all, a_pre, a_post, a_res,
                                                 perm, params, li);
    k_gemm_out<<<dim3(64, 16), dim3(256), 0, stream>>>(li, wlayer_b, b_layer, params, x, out);
}